// Round 8
// baseline (329.736 us; speedup 1.0000x reference)
//
#include <hip/hip_runtime.h>

#define HID 10
#define STEPS 512

typedef __attribute__((ext_vector_type(2))) float v2f;
typedef __attribute__((ext_vector_type(4))) float v4f;

// broadcast lane ((lane&0x10)|F) within each 32-lane half -> all lanes of each 16-group
// (one-time use: t=0 peel)
template<int F>
static __device__ __forceinline__ float swz(float v) {
    return __int_as_float(__builtin_amdgcn_ds_swizzle(__float_as_int(v), (F << 5) | 0x10));
}

// Lane-parallel fused GRU decoder, 1 feature per lane, EIGHT batches per wave
// as two independent streams (A = blockIdx*8+g, B = +4), grid 1024 = 1 wave/SIMD.
// v8 rationale: v7 measured 723 cyc/SIMD-step = issue(434) + chain(300) EXACTLY —
// the two co-resident waves ran in lockstep convoy (fair round-robin issue
// re-synchronizes identical waves; sleep-stagger provably dissolved). TLP can't
// overlap the chain; in-wave ILP can: the compiler statically interleaves the
// two streams, so B's issue fills A's LDS-gather (~140cy) + trans-tail stalls
// and vice versa. Weight tables are per-feature -> SHARED by both streams.
// No fences in the loop: LDS write/read alias the same array (order pinned),
// VALU of the other stream stays free to move across (the v5 wave_barrier
// would forbid exactly the overlap we need).
__global__ __launch_bounds__(64, 1) void gru_decoder_kernel(
    const float* __restrict__ hidden, const float* __restrict__ w_ih,
    const float* __restrict__ w_hh, const float* __restrict__ b_ih,
    const float* __restrict__ b_hh, const float* __restrict__ l1_w,
    const float* __restrict__ l1_b, const float* __restrict__ l2_w,
    const float* __restrict__ l2_b, float* __restrict__ out)
{
    __shared__ float sWx[640];   // l2_w @ l1_w (64x10)
    __shared__ float sbx[64];    // l2_w @ l1_b + l2_b
    __shared__ float sWgi[300];  // w_ih @ Wx (30x10)
    __shared__ float sbgi[30];   // b_ih + w_ih @ bx
    __shared__ float sWhh[300];  // w_hh copy (t=0 peel + weight build)
    __shared__ float sH[128];    // 8 rows x 16 floats (A: rows 0-3, B: rows 4-7)

    const int lane = threadIdx.x;
    const int f    = lane & 15;
    const int g    = lane >> 4;
    const int bA   = blockIdx.x * 8 + g;
    const int bB   = bA + 4;
    const bool ok  = (f < HID);
    const int fi   = ok ? f : 0;          // clamped index for safe reads

    // ---- preamble: fused weights (fp32, cooperative) ----
    for (int e = lane; e < 640; e += 64) {
        int i = e / 10, j = e - i * 10;
        float acc = 0.f;
        #pragma unroll
        for (int k = 0; k < 10; ++k) acc += l2_w[i * 10 + k] * l1_w[k * 10 + j];
        sWx[e] = acc;
    }
    {
        float acc = l2_b[lane];
        #pragma unroll
        for (int k = 0; k < 10; ++k) acc += l2_w[lane * 10 + k] * l1_b[k];
        sbx[lane] = acc;
    }
    for (int e = lane; e < 300; e += 64) sWhh[e] = w_hh[e];
    __syncthreads();
    for (int e = lane; e < 300; e += 64) {
        int m = e / 10, j = e - m * 10;
        float acc = 0.f;
        for (int k = 0; k < 64; ++k) acc += w_ih[m * 64 + k] * sWx[k * 10 + j];
        sWgi[e] = acc;
    }
    if (lane < 30) {
        float acc = b_ih[lane];
        for (int k = 0; k < 64; ++k) acc += w_ih[lane * 64 + k] * sbx[k];
        sbgi[lane] = acc;
    }
    __syncthreads();

    const float LOG2E = 1.4426950408889634f;
    const float S2    = 2.f * LOG2E;

    // ---- per-lane weights (feature fi), packed across k (even/odd); shared A/B ----
    v2f wr2[5], wz2[5], wi2[5], wh2[5], wo2[5];
    #pragma unroll
    for (int k2 = 0; k2 < 5; ++k2) {
        int k0 = 2 * k2, k1 = 2 * k2 + 1;
        float r0 = -(sWgi[fi * 10 + k0] + sWhh[fi * 10 + k0]) * LOG2E;
        float r1 = -(sWgi[fi * 10 + k1] + sWhh[fi * 10 + k1]) * LOG2E;
        float z0 = -(sWgi[(10 + fi) * 10 + k0] + sWhh[(10 + fi) * 10 + k0]) * LOG2E;
        float z1 = -(sWgi[(10 + fi) * 10 + k1] + sWhh[(10 + fi) * 10 + k1]) * LOG2E;
        float i0 = sWgi[(20 + fi) * 10 + k0] * S2;
        float i1 = sWgi[(20 + fi) * 10 + k1] * S2;
        float hh0 = sWhh[(20 + fi) * 10 + k0] * S2;
        float hh1 = sWhh[(20 + fi) * 10 + k1] * S2;
        float o0 = l1_w[fi * 10 + k0];
        float o1 = l1_w[fi * 10 + k1];
        wr2[k2] = ok ? v2f{r0, r1}   : v2f{0.f, 0.f};
        wz2[k2] = ok ? v2f{z0, z1}   : v2f{0.f, 0.f};
        wi2[k2] = ok ? v2f{i0, i1}   : v2f{0.f, 0.f};
        wh2[k2] = ok ? v2f{hh0, hh1} : v2f{0.f, 0.f};
        wo2[k2] = ok ? v2f{o0, o1}   : v2f{0.f, 0.f};
    }
    const float br = ok ? -(sbgi[fi] + b_hh[fi]) * LOG2E : 0.f;
    const float bz = ok ? -(sbgi[10 + fi] + b_hh[10 + fi]) * LOG2E : 0.f;
    const float bi = ok ? sbgi[20 + fi] * S2 : 0.f;
    const float bh = ok ? b_hh[20 + fi] * S2 : 0.f;
    const float bo = ok ? l1_b[fi] : 0.f;
    const v2f BR2 = {br, 0.f}, BZ2 = {bz, 0.f}, BI2 = {bi, 0.f},
              BH2 = {bh, 0.f}, BO2 = {bo, 0.f};
    // t=0 peel biases (gi = b_ih only)
    const float br0_ = ok ? -(b_ih[fi] + b_hh[fi]) * LOG2E : 0.f;
    const float bz0_ = ok ? -(b_ih[10 + fi] + b_hh[10 + fi]) * LOG2E : 0.f;
    const float bni0 = ok ? b_ih[20 + fi] * S2 : 0.f;

    // ---- initial h for both streams (f>=10 stays exactly 0) ----
    float hA = ok ? hidden[(size_t)bA * HID + f] : 0.f;
    float hB = ok ? hidden[(size_t)bB * HID + f] : 0.f;

    float* pbA = out + (size_t)bA * (STEPS * HID) + (size_t)(STEPS - 1) * HID + f;
    float* pbB = out + (size_t)bB * (STEPS * HID) + (size_t)(STEPS - 1) * HID + f;
    float* rowA = &sH[g * 16];
    float* rowB = &sH[(4 + g) * 16];

    // ---- t = 0 peel (gi = b_ih only; x_0 = 0) for both streams ----
    auto peel0 = [&](float& h) {
        float ha[10];
        ha[0] = swz<0>(h); ha[1] = swz<1>(h); ha[2] = swz<2>(h);
        ha[3] = swz<3>(h); ha[4] = swz<4>(h); ha[5] = swz<5>(h);
        ha[6] = swz<6>(h); ha[7] = swz<7>(h); ha[8] = swz<8>(h);
        ha[9] = swz<9>(h);
        float pr = 0.f, pz = 0.f, ph = 0.f;
        #pragma unroll
        for (int k = 0; k < 10; ++k) {
            pr += sWhh[fi * 10 + k] * ha[k];
            pz += sWhh[(10 + fi) * 10 + k] * ha[k];
            ph += sWhh[(20 + fi) * 10 + k] * ha[k];
        }
        float vr = br0_ - pr * LOG2E;
        float vz = bz0_ - pz * LOG2E;
        float r = __builtin_amdgcn_rcpf(1.f + __builtin_amdgcn_exp2f(vr));
        float z = __builtin_amdgcn_rcpf(1.f + __builtin_amdgcn_exp2f(vz));
        float y = bni0 + r * (ph * S2 + bh);
        float n = 1.f - 2.f * __builtin_amdgcn_rcpf(1.f + __builtin_amdgcn_exp2f(y));
        h = ok ? (n + z * (h - n)) : 0.f;
    };
    peel0(hA);
    peel0(hB);

    // ---- pre-loop stage: write h_1, read gather regs for both streams ----
    rowA[f] = hA;
    rowB[f] = hB;
    __builtin_amdgcn_wave_barrier();      // one-time ordering (outside hot loop)
    v4f qA0 = *(const v4f*)(rowA); v4f qA1 = *(const v4f*)(rowA + 4);
    v2f qA2 = *(const v2f*)(rowA + 8);
    v4f qB0 = *(const v4f*)(rowB); v4f qB1 = *(const v4f*)(rowB + 4);
    v2f qB2 = *(const v2f*)(rowB + 8);

    // one full GRU step for one stream from its gathered regs (h_t) -> h_{t+1}, o_{t-1}
    auto gru_step = [&](v4f q0, v4f q1, v2f q2, float& h, float& o) {
        v2f h2_0 = __builtin_shufflevector(q0, q0, 0, 1);
        v2f h2_1 = __builtin_shufflevector(q0, q0, 2, 3);
        v2f h2_2 = __builtin_shufflevector(q1, q1, 0, 1);
        v2f h2_3 = __builtin_shufflevector(q1, q1, 2, 3);
        v2f h2_4 = q2;
        v2f ar = wr2[0] * h2_0 + BR2;
        v2f az = wz2[0] * h2_0 + BZ2;
        v2f ai = wi2[0] * h2_0 + BI2;
        v2f ah = wh2[0] * h2_0 + BH2;
        v2f ao = wo2[0] * h2_0 + BO2;
        ar += wr2[1] * h2_1; az += wz2[1] * h2_1; ai += wi2[1] * h2_1;
        ah += wh2[1] * h2_1; ao += wo2[1] * h2_1;
        ar += wr2[2] * h2_2; az += wz2[2] * h2_2; ai += wi2[2] * h2_2;
        ah += wh2[2] * h2_2; ao += wo2[2] * h2_2;
        ar += wr2[3] * h2_3; az += wz2[3] * h2_3; ai += wi2[3] * h2_3;
        ah += wh2[3] * h2_3; ao += wo2[3] * h2_3;
        ar += wr2[4] * h2_4; az += wz2[4] * h2_4; ai += wi2[4] * h2_4;
        ah += wh2[4] * h2_4; ao += wo2[4] * h2_4;
        float arx = ar.x + ar.y;
        float azx = az.x + az.y;
        float aix = ai.x + ai.y;
        float ahx = ah.x + ah.y;
        o = ao.x + ao.y;                  // = l1(h_t) = o_{t-1}
        // fused z/n update, single rcp: h' = (ez(en-1)+h(en+1)) / ((en+1)(1+ez))
        float er = __builtin_amdgcn_exp2f(arx);
        float r  = __builtin_amdgcn_rcpf(1.f + er);
        float ez = __builtin_amdgcn_exp2f(azx);
        float y  = __builtin_fmaf(r, ahx, aix);
        float en = __builtin_amdgcn_exp2f(y);
        float p  = en * ez;
        float tt = h - ez;
        float u  = p + tt;
        float num = __builtin_fmaf(h, en, u);
        float v   = en + ez;
        float den = (p + v) + 1.f;
        h = num * __builtin_amdgcn_rcpf(den);   // padded lanes: h stays 0
    };

    // ---- t = 1 .. 511 : two phase-split streams; each stream's LDS round-trip
    //      and trans tail hide under the other stream's independent issue ----
    #pragma unroll 1
    for (int t = 1; t < STEPS; ++t) {
        float oA, oB;
        // stream A
        gru_step(qA0, qA1, qA2, hA, oA);
        rowA[f] = hA;                          // aliasing pins write->read order
        qA0 = *(const v4f*)(rowA);
        qA1 = *(const v4f*)(rowA + 4);
        qA2 = *(const v2f*)(rowA + 8);
        // stream B
        gru_step(qB0, qB1, qB2, hB, oB);
        rowB[f] = hB;
        qB0 = *(const v4f*)(rowB);
        qB1 = *(const v4f*)(rowB + 4);
        qB2 = *(const v2f*)(rowB + 8);
        // pipelined stores: o_{t-1} at position STEPS-t
        if (ok) { pbA[0] = oA; pbB[0] = oB; }
        pbA -= HID; pbB -= HID;
    }

    // ---- epilogue: o_511 = l1(h_512) at position 0 (qA/qB hold h_512) ----
    {
        v2f aoA = wo2[0] * __builtin_shufflevector(qA0, qA0, 0, 1) + BO2;
        aoA += wo2[1] * __builtin_shufflevector(qA0, qA0, 2, 3);
        aoA += wo2[2] * __builtin_shufflevector(qA1, qA1, 0, 1);
        aoA += wo2[3] * __builtin_shufflevector(qA1, qA1, 2, 3);
        aoA += wo2[4] * qA2;
        v2f aoB = wo2[0] * __builtin_shufflevector(qB0, qB0, 0, 1) + BO2;
        aoB += wo2[1] * __builtin_shufflevector(qB0, qB0, 2, 3);
        aoB += wo2[2] * __builtin_shufflevector(qB1, qB1, 0, 1);
        aoB += wo2[3] * __builtin_shufflevector(qB1, qB1, 2, 3);
        aoB += wo2[4] * qB2;
        if (ok) { pbA[0] = aoA.x + aoA.y; pbB[0] = aoB.x + aoB.y; }
    }
}

extern "C" void kernel_launch(void* const* d_in, const int* in_sizes, int n_in,
                              void* d_out, int out_size, void* d_ws, size_t ws_size,
                              hipStream_t stream) {
    (void)in_sizes; (void)n_in; (void)d_ws; (void)ws_size; (void)out_size;
    dim3 grid(1024), block(64);   // 8 batches/wave (2 streams), 1024 waves = 1/SIMD
    gru_decoder_kernel<<<grid, block, 0, stream>>>(
        (const float*)d_in[0], (const float*)d_in[1], (const float*)d_in[2],
        (const float*)d_in[3], (const float*)d_in[4], (const float*)d_in[5],
        (const float*)d_in[6], (const float*)d_in[7], (const float*)d_in[8],
        (float*)d_out);
}